// Round 3
// baseline (723.994 us; speedup 1.0000x reference)
//
#include <hip/hip_runtime.h>
#include <math.h>

#define NUM_USERS 200000
#define NUM_PRODUCTS 100000
#define N_NODES 300000
#define N_EDGES 1000000
#define EDIM 64
#define FDIM 128
#define CAP 40            // fixed adjacency capacity/node; max degree ~27 (Poisson(10) tail)
#define FILL_T 250000     // threads in fill = N_EDGES/4
#define LDST 72           // LDS tile row stride in u16 (144 B: 16B-aligned, breaks pow2 banks)
#define NT_U 12500        // user tiles
#define NT_ALL 18750      // total node tiles
#define ZERO_BLK 1172     // 1172*256 = 300032 ints zeroed

typedef __attribute__((ext_vector_type(8))) short short8;   // 8 bf16 in 4 VGPRs
typedef __attribute__((ext_vector_type(4))) float f32x4;    // MFMA accumulator

// fp32 -> bf16 round-to-nearest-even
static __device__ inline short f2bf(float f) {
    unsigned int u = __float_as_uint(f);
    unsigned int r = (u + 0x7FFFu + ((u >> 16) & 1u)) >> 16;
    return (short)r;
}
static __device__ inline float bf2f(unsigned short s) {
    return __uint_as_float(((unsigned int)s) << 16);
}
// deg^-1/2 with self-loop; same v_rsq_f32 the old k_dis used -> bit-identical numerics
static __device__ inline float disf(int c) {
    return rsqrtf(1.0f + (float)c);
}

// ---------------- setup: zero cnt + weight prep (bf16, transposed [n][k]) ----------------
// wts layout (shorts): WufT@0(8192) WpfT@8192(8192) c1T@16384(4096) c2T@20480(4096) W1T@24576(8192)
__global__ void k_setup(int* __restrict__ cnt,
                        const float* __restrict__ W_uf, const float* __restrict__ W_pf,
                        const float* __restrict__ c1, const float* __restrict__ c2,
                        const float* __restrict__ W1, short* __restrict__ wts) {
    int b = blockIdx.x;
    if (b < ZERO_BLK) {
        int i = b * 256 + threadIdx.x;
        if (i < 300032) cnt[i] = 0;
        return;
    }
    int gid = (b - ZERO_BLK) * 256 + threadIdx.x;
    if (gid >= 32768) return;
    if (gid < 8192) {
        int n = gid >> 7, k = gid & 127;
        wts[gid] = f2bf(W_uf[k * 64 + n]);
    } else if (gid < 16384) {
        int i = gid - 8192; int n = i >> 7, k = i & 127;
        wts[gid] = f2bf(W_pf[k * 64 + n]);
    } else if (gid < 20480) {
        int i = gid - 16384; int n = i >> 6, k = i & 63;
        wts[gid] = f2bf(c1[k * 64 + n]);
    } else if (gid < 24576) {
        int i = gid - 20480; int n = i >> 6, k = i & 63;
        wts[gid] = f2bf(c2[k * 64 + n]);
    } else {
        int i = gid - 24576; int n = i >> 7, k = i & 127;
        wts[gid] = f2bf(W1[k * 64 + n]);
    }
}

// ---------------- direct CSR fill: one pass, atomic return = slot rank ----------------
__global__ __launch_bounds__(256) void k_fill_direct(
    const int* __restrict__ ei, int* __restrict__ cnt, int* __restrict__ adj) {
    int t = blockIdx.x * 256 + threadIdx.x;
    if (t >= FILL_T) return;
    int u[4], p[4], pu[4], pp[4];
#pragma unroll
    for (int j = 0; j < 4; ++j) {
        int e = t + j * FILL_T;
        u[j] = ei[e];
        p[j] = ei[N_EDGES + e];   // reference quirk: raw (un-offset) product idx
    }
#pragma unroll
    for (int j = 0; j < 4; ++j) {
        pp[j] = atomicAdd(&cnt[p[j]], 1);
        pu[j] = atomicAdd(&cnt[u[j]], 1);
    }
#pragma unroll
    for (int j = 0; j < 4; ++j) {
        adj[(size_t)p[j] * CAP + pp[j]] = u[j];   // dest p receives h'[u]
        adj[(size_t)u[j] * CAP + pu[j]] = p[j];   // dest u receives h'[p]
    }
}

// ---------------- FUSED: x0 = feat@W + b + emb; h1' = dis*(x0@c1W) ----------------
// Single dispatch covers users AND products (wave-uniform branch on tile id).
// x0 never touches global memory: LDS retile (2.25 KB/wave) bridges the two MFMA GEMMs.
__global__ __launch_bounds__(256) void k_xform_c1(
    const float* __restrict__ user_feat, const float* __restrict__ prod_feat,
    const short* __restrict__ wts,
    const float* __restrict__ b_uf, const float* __restrict__ b_pf,
    const float* __restrict__ user_emb, const float* __restrict__ prod_emb,
    const int* __restrict__ cnt, unsigned short* __restrict__ h) {
    __shared__ unsigned short lds[4][16 * LDST];
    int tid = threadIdx.x;
    int wave = tid >> 6;
    int tile = blockIdx.x * 4 + wave;
    if (tile >= NT_ALL) tile = NT_ALL - 1;   // clamp: duplicate identical writes, keeps barrier safe
    int lane = tid & 63, ln = lane & 15, quad = lane >> 4;

    // per-wave operand selection (uniform within wave -> no divergence)
    const float* feat; const short* WT; const float* b; const float* emb;
    int node_off, mtile;
    if (tile < NT_U) {
        feat = user_feat; WT = wts;        b = b_uf; emb = user_emb; node_off = 0;         mtile = tile;
    } else {
        feat = prod_feat; WT = wts + 8192; b = b_pf; emb = prod_emb; node_off = NUM_USERS; mtile = tile - NT_U;
    }
    const short* c1T = wts + 16384;

    short8 Bx[4][4];
#pragma unroll
    for (int t = 0; t < 4; ++t)
#pragma unroll
        for (int kk = 0; kk < 4; ++kk)
            Bx[t][kk] = *(const short8*)(WT + ((t * 16 + ln) * 128 + kk * 32 + quad * 8));
    short8 Bc[4][2];
#pragma unroll
    for (int t = 0; t < 4; ++t)
#pragma unroll
        for (int kk = 0; kk < 2; ++kk)
            Bc[t][kk] = *(const short8*)(c1T + ((t * 16 + ln) * 64 + kk * 32 + quad * 8));
    float bv[4];
#pragma unroll
    for (int t = 0; t < 4; ++t) bv[t] = b[t * 16 + ln];

    int mbase = mtile * 16;
    const float* arow = feat + (size_t)(mbase + ln) * FDIM + quad * 8;

    f32x4 acc[4] = {{0.f,0.f,0.f,0.f},{0.f,0.f,0.f,0.f},{0.f,0.f,0.f,0.f},{0.f,0.f,0.f,0.f}};
#pragma unroll
    for (int kk = 0; kk < 4; ++kk) {
        float4 lo = *(const float4*)(arow + kk * 32);
        float4 hi = *(const float4*)(arow + kk * 32 + 4);
        short8 Af;
        Af[0] = f2bf(lo.x); Af[1] = f2bf(lo.y); Af[2] = f2bf(lo.z); Af[3] = f2bf(lo.w);
        Af[4] = f2bf(hi.x); Af[5] = f2bf(hi.y); Af[6] = f2bf(hi.z); Af[7] = f2bf(hi.w);
#pragma unroll
        for (int t = 0; t < 4; ++t)
            acc[t] = __builtin_amdgcn_mfma_f32_16x16x32_bf16(Af, Bx[t][kk], acc[t], 0, 0, 0);
    }
    // x0 epilogue -> LDS tile (bf16, same quantization the old memory round-trip applied)
#pragma unroll
    for (int r = 0; r < 4; ++r) {
        int node = mbase + quad * 4 + r;
#pragma unroll
        for (int t = 0; t < 4; ++t) {
            float v = acc[t][r] + bv[t] + emb[(size_t)node * EDIM + t * 16 + ln];
            lds[wave][(quad * 4 + r) * LDST + t * 16 + ln] = (unsigned short)f2bf(v);
        }
    }
    __syncthreads();
    // second GEMM: h1' = dis * (x0 @ c1W)
    f32x4 acch[4] = {{0.f,0.f,0.f,0.f},{0.f,0.f,0.f,0.f},{0.f,0.f,0.f,0.f},{0.f,0.f,0.f,0.f}};
#pragma unroll
    for (int kk = 0; kk < 2; ++kk) {
        short8 Af = *(const short8*)(&lds[wave][ln * LDST + kk * 32 + quad * 8]);
#pragma unroll
        for (int t = 0; t < 4; ++t)
            acch[t] = __builtin_amdgcn_mfma_f32_16x16x32_bf16(Af, Bc[t][kk], acch[t], 0, 0, 0);
    }
    float disv[4];
#pragma unroll
    for (int r = 0; r < 4; ++r) disv[r] = disf(cnt[node_off + mbase + quad * 4 + r]);
#pragma unroll
    for (int r = 0; r < 4; ++r) {
        int node = mbase + quad * 4 + r;
#pragma unroll
        for (int t = 0; t < 4; ++t)
            h[(size_t)(node_off + node) * EDIM + t * 16 + ln] =
                (unsigned short)f2bf(disv[r] * acch[t][r]);
    }
}

// ---------------- FUSED: x1 = relu(dis*(h1'[d]+Σ h1'[src]) + b1); h2' = dis*(x1@c2W) ----------------
// One wave builds a full 16-node tile: 4 nodes concurrently (16 lanes/node, 2 u32 feats/lane),
// 4 sequential node-quads, then LDS tile -> MFMA. x1 never touches global memory.
__global__ __launch_bounds__(256) void k_gather_c2(
    const int* __restrict__ adj, const int* __restrict__ cnt,
    const unsigned short* __restrict__ h,
    const float* __restrict__ b1, const short* __restrict__ c2T,
    unsigned short* __restrict__ hout) {
    __shared__ unsigned short lds[4][16 * LDST];
    int tid = threadIdx.x;
    int wave = tid >> 6;
    int tile = blockIdx.x * 4 + wave;
    if (tile >= N_NODES / 16) tile = N_NODES / 16 - 1;  // clamp (benign dup writes)
    int lane = tid & 63, ln = lane & 15, quad = lane >> 4;
    const unsigned int* hp = (const unsigned int*)h;    // bf16x2 view, row stride 32

    short8 Bc[4][2];
#pragma unroll
    for (int t = 0; t < 4; ++t)
#pragma unroll
        for (int kk = 0; kk < 2; ++kk)
            Bc[t][kk] = *(const short8*)(c2T + ((t * 16 + ln) * 64 + kk * 32 + quad * 8));

    int mbase = tile * 16;
    float2 bb0 = ((const float2*)b1)[ln];        // feats 2ln, 2ln+1
    float2 bb1 = ((const float2*)b1)[16 + ln];   // feats 32+2ln, 32+2ln+1

#pragma unroll 1
    for (int it = 0; it < 4; ++it) {
        int d = mbase + it * 4 + quad;
        const unsigned int* hrow = hp + (size_t)d * 32;
        unsigned int s0 = hrow[ln], s1 = hrow[16 + ln];          // self-loop term
        float a0 = bf2f((unsigned short)s0);
        float a1 = bf2f((unsigned short)(s0 >> 16));
        float a2 = bf2f((unsigned short)s1);
        float a3 = bf2f((unsigned short)(s1 >> 16));
        int cd = cnt[d];
        const int* ap = adj + (size_t)d * CAP;
        int i = 0;
        for (; i + 1 < cd; i += 2) {                             // 4 gathers in flight/lane
            int r0 = ap[i], r1 = ap[i + 1];
            unsigned int p00 = hp[(size_t)r0 * 32 + ln];
            unsigned int p01 = hp[(size_t)r0 * 32 + 16 + ln];
            unsigned int p10 = hp[(size_t)r1 * 32 + ln];
            unsigned int p11 = hp[(size_t)r1 * 32 + 16 + ln];
            a0 += bf2f((unsigned short)p00) + bf2f((unsigned short)p10);
            a1 += bf2f((unsigned short)(p00 >> 16)) + bf2f((unsigned short)(p10 >> 16));
            a2 += bf2f((unsigned short)p01) + bf2f((unsigned short)p11);
            a3 += bf2f((unsigned short)(p01 >> 16)) + bf2f((unsigned short)(p11 >> 16));
        }
        if (i < cd) {
            int r0 = ap[i];
            unsigned int p00 = hp[(size_t)r0 * 32 + ln];
            unsigned int p01 = hp[(size_t)r0 * 32 + 16 + ln];
            a0 += bf2f((unsigned short)p00);
            a1 += bf2f((unsigned short)(p00 >> 16));
            a2 += bf2f((unsigned short)p01);
            a3 += bf2f((unsigned short)(p01 >> 16));
        }
        float dv = disf(cd);
        float v0 = fmaxf(fmaf(dv, a0, bb0.x), 0.f);
        float v1 = fmaxf(fmaf(dv, a1, bb0.y), 0.f);
        float v2 = fmaxf(fmaf(dv, a2, bb1.x), 0.f);
        float v3 = fmaxf(fmaf(dv, a3, bb1.y), 0.f);
        unsigned int* lrow = (unsigned int*)&lds[wave][(it * 4 + quad) * LDST];
        lrow[ln] = ((unsigned int)(unsigned short)f2bf(v1) << 16)
                 | (unsigned int)(unsigned short)f2bf(v0);
        lrow[16 + ln] = ((unsigned int)(unsigned short)f2bf(v3) << 16)
                      | (unsigned int)(unsigned short)f2bf(v2);
    }
    __syncthreads();
    // h2' = dis * (x1 @ c2W)
    f32x4 acc[4] = {{0.f,0.f,0.f,0.f},{0.f,0.f,0.f,0.f},{0.f,0.f,0.f,0.f},{0.f,0.f,0.f,0.f}};
#pragma unroll
    for (int kk = 0; kk < 2; ++kk) {
        short8 Af = *(const short8*)(&lds[wave][ln * LDST + kk * 32 + quad * 8]);
#pragma unroll
        for (int t = 0; t < 4; ++t)
            acc[t] = __builtin_amdgcn_mfma_f32_16x16x32_bf16(Af, Bc[t][kk], acc[t], 0, 0, 0);
    }
    float disv[4];
#pragma unroll
    for (int r = 0; r < 4; ++r) disv[r] = disf(cnt[mbase + quad * 4 + r]);
#pragma unroll
    for (int r = 0; r < 4; ++r) {
        int node = mbase + quad * 4 + r;
#pragma unroll
        for (int t = 0; t < 4; ++t)
            hout[(size_t)node * EDIM + t * 16 + ln] = (unsigned short)f2bf(disv[r] * acc[t][r]);
    }
}

// ---------------- gather + finish (conv2 output): x[d] = dis[d]*(h'[d]+Σ h'[src]) + b ----------------
__global__ __launch_bounds__(256) void k_gather(
    const int* __restrict__ adj, const int* __restrict__ cnt,
    const unsigned short* __restrict__ h,
    const float* __restrict__ b, unsigned short* __restrict__ xout, int relu) {
    int d = blockIdx.x * 4 + (threadIdx.x >> 6);
    if (d >= N_NODES) return;
    int l = threadIdx.x & 63;
    int half = l >> 5, c2 = l & 31;              // feature pair c2 -> feats {2c2, 2c2+1}
    const unsigned int* hp = (const unsigned int*)h;   // bf16x2 view, row stride 32

    float ax = 0.f, ay = 0.f;
    if (half == 0) {                              // self-loop term, counted once
        unsigned int pr = hp[(size_t)d * 32 + c2];
        ax = bf2f((unsigned short)pr);
        ay = bf2f((unsigned short)(pr >> 16));
    }
    int c = cnt[d];
    const int* ap = adj + (size_t)d * CAP;
    int i = 0;
    for (; i + 3 < c; i += 4) {
        int s0 = ap[i + half];
        int s1 = ap[i + 2 + half];
        unsigned int p0 = hp[(size_t)s0 * 32 + c2];
        unsigned int p1 = hp[(size_t)s1 * 32 + c2];
        ax += bf2f((unsigned short)p0) + bf2f((unsigned short)p1);
        ay += bf2f((unsigned short)(p0 >> 16)) + bf2f((unsigned short)(p1 >> 16));
    }
    if (i + half < c) {
        unsigned int p0 = hp[(size_t)ap[i + half] * 32 + c2];
        ax += bf2f((unsigned short)p0);
        ay += bf2f((unsigned short)(p0 >> 16));
    }
    if (i + 2 + half < c) {
        unsigned int p0 = hp[(size_t)ap[i + 2 + half] * 32 + c2];
        ax += bf2f((unsigned short)p0);
        ay += bf2f((unsigned short)(p0 >> 16));
    }
    ax += __shfl_xor(ax, 32, 64);                 // combine the two halves
    ay += __shfl_xor(ay, 32, 64);
    float dv = disf(c);
    float2 bb = ((const float2*)b)[c2];
    float v0 = fmaf(dv, ax, bb.x);
    float v1 = fmaf(dv, ay, bb.y);
    if (relu) { v0 = fmaxf(v0, 0.f); v1 = fmaxf(v1, 0.f); }
    if (half == 0) {
        unsigned int pk = ((unsigned int)(unsigned short)f2bf(v1) << 16)
                        | (unsigned int)(unsigned short)f2bf(v0);
        ((unsigned int*)xout)[(size_t)d * 32 + c2] = pk;
    }
}

// ---------------- edge predictor via bf16 MFMA, ei prefetch + hoisted A loads ----------------
__global__ __launch_bounds__(256) void k_pred_mfma(
    const int* __restrict__ ei, const unsigned short* __restrict__ x,
    const short* __restrict__ W1T, const float* __restrict__ b1,
    const float* __restrict__ W2, const float* __restrict__ b2,
    float* __restrict__ preds) {
    int tid = threadIdx.x;
    int wave = tid >> 6, lane = tid & 63;
    int ln = lane & 15, quad = lane >> 4;

    short8 Bf[4][4];
#pragma unroll
    for (int t = 0; t < 4; ++t)
#pragma unroll
        for (int kk = 0; kk < 4; ++kk)
            Bf[t][kk] = *(const short8*)(W1T + ((t * 16 + ln) * 128 + kk * 32 + quad * 8));

    float b1v[4], W2v[4];
#pragma unroll
    for (int t = 0; t < 4; ++t) {
        b1v[t] = b1[t * 16 + ln];
        W2v[t] = W2[t * 16 + ln];
    }
    float b2s = b2[0];

    const int n_tiles = N_EDGES / 16;
    int gw = blockIdx.x * 4 + wave;
    int nwaves = gridDim.x * 4;

    int cu = 0, cp = 0;
    if (gw < n_tiles) {
        cu = ei[gw * 16 + ln];
        cp = ei[N_EDGES + gw * 16 + ln] + NUM_USERS;
    }
    for (int tile = gw; tile < n_tiles; tile += nwaves) {
        int u = cu, p = cp;
        int nt = tile + nwaves;
        if (nt < n_tiles) {                       // prefetch next tile's indices
            cu = ei[nt * 16 + ln];
            cp = ei[N_EDGES + nt * 16 + ln] + NUM_USERS;
        }
        short8 Af[4];                             // all 4 A loads in flight
        Af[0] = *(const short8*)(x + (size_t)u * EDIM + quad * 8);
        Af[1] = *(const short8*)(x + (size_t)u * EDIM + 32 + quad * 8);
        Af[2] = *(const short8*)(x + (size_t)p * EDIM + quad * 8);
        Af[3] = *(const short8*)(x + (size_t)p * EDIM + 32 + quad * 8);

        f32x4 acc[4] = {{0.f,0.f,0.f,0.f},{0.f,0.f,0.f,0.f},{0.f,0.f,0.f,0.f},{0.f,0.f,0.f,0.f}};
#pragma unroll
        for (int kk = 0; kk < 4; ++kk)
#pragma unroll
            for (int t = 0; t < 4; ++t)
                acc[t] = __builtin_amdgcn_mfma_f32_16x16x32_bf16(Af[kk], Bf[t][kk], acc[t], 0, 0, 0);

        float out[4];
#pragma unroll
        for (int r = 0; r < 4; ++r) {
            float part = 0.f;
#pragma unroll
            for (int t = 0; t < 4; ++t) {
                float hv = fmaxf(acc[t][r] + b1v[t], 0.f);
                part = fmaf(hv, W2v[t], part);
            }
            part += __shfl_xor(part, 1, 64);
            part += __shfl_xor(part, 2, 64);
            part += __shfl_xor(part, 4, 64);
            part += __shfl_xor(part, 8, 64);
            out[r] = part;
        }
        if (ln == 0) {
            int ebase = tile * 16;
#pragma unroll
            for (int r = 0; r < 4; ++r) {
                float logit = out[r] + b2s;
                preds[ebase + quad * 4 + r] = 5.f / (1.f + expf(-logit));
            }
        }
    }
}

extern "C" void kernel_launch(void* const* d_in, const int* in_sizes, int n_in,
                              void* d_out, int out_size, void* d_ws, size_t ws_size,
                              hipStream_t stream) {
    const int*   ei        = (const int*)d_in[0];
    const float* user_feat = (const float*)d_in[1];
    const float* prod_feat = (const float*)d_in[2];
    const float* user_emb  = (const float*)d_in[3];
    const float* prod_emb  = (const float*)d_in[4];
    const float* W_uf      = (const float*)d_in[5];
    const float* b_uf      = (const float*)d_in[6];
    const float* W_pf      = (const float*)d_in[7];
    const float* b_pf      = (const float*)d_in[8];
    const float* conv1_W   = (const float*)d_in[9];
    const float* conv1_b   = (const float*)d_in[10];
    const float* conv2_W   = (const float*)d_in[11];
    const float* conv2_b   = (const float*)d_in[12];
    const float* pred_W1   = (const float*)d_in[13];
    const float* pred_b1   = (const float*)d_in[14];
    const float* pred_W2   = (const float*)d_in[15];
    const float* pred_b2   = (const float*)d_in[16];

    // workspace layout (4-byte units) — offsets kept from prior rounds; dis slot now unused
    int* ws_i = (int*)d_ws;
    int*   cnt  = ws_i;                            // 300032
    int*   adj  = ws_i + 600064;                   // 300032*40 = 12,001,280
    unsigned short* xbuf = (unsigned short*)(ws_i + 12601344);  // 19.2M bf16
    unsigned short* hbuf = (unsigned short*)(ws_i + 22201344);  // 19.2M bf16
    short* wts = (short*)(ws_i + 31801344);        // 32768 bf16
    float* preds = (float*)d_out;

    // setup (zero cnt + weight prep, one dispatch) then CSR build
    k_setup<<<ZERO_BLK + 128, 256, 0, stream>>>(cnt, W_uf, W_pf, conv1_W, conv2_W, pred_W1, wts);
    k_fill_direct<<<(FILL_T + 255) / 256, 256, 0, stream>>>(ei, cnt, adj);

    // fused node-transform + conv1 GEMM (users+products, one dispatch) -> hbuf = h1'
    k_xform_c1<<<(NT_ALL + 3) / 4, 256, 0, stream>>>(user_feat, prod_feat, wts,
                                                     b_uf, b_pf, user_emb, prod_emb,
                                                     cnt, hbuf);

    // fused conv1-gather + conv2 GEMM -> xbuf = h2'; x1 never hits memory
    k_gather_c2<<<(18750 + 3) / 4, 256, 0, stream>>>(adj, cnt, hbuf, conv1_b,
                                                     wts + 20480, xbuf);
    // conv2 gather -> hbuf = x2 (final node embeddings)
    k_gather<<<N_NODES / 4, 256, 0, stream>>>(adj, cnt, xbuf, conv2_b, hbuf, 0);

    // predictor
    k_pred_mfma<<<2048, 256, 0, stream>>>(ei, hbuf, wts + 24576, pred_b1, pred_W2, pred_b2, preds);
}

// Round 4
// 681.578 us; speedup vs baseline: 1.0622x; 1.0622x over previous
//
#include <hip/hip_runtime.h>
#include <math.h>

#define NUM_USERS 200000
#define NUM_PRODUCTS 100000
#define N_NODES 300000
#define N_EDGES 1000000
#define EDIM 64
#define FDIM 128
#define CAP 40            // fixed adjacency capacity/node; max degree ~27 (Poisson(10) tail)
#define LDST 72           // LDS tile row stride in u16 (144 B: 16B-aligned, breaks pow2 banks)
#define NT_U 12500        // user tiles
#define NT_ALL 18750      // total node tiles
#define ZERO_BLK 1173     // 1173*256 = 300288 >= 300032 cnt + 80 bucket counters
#define NBUK 80           // CSR bins: dest in [0,200000), 2500 nodes/bucket (400KB adj region)
#define BNODES 2500
#define BINCAP 49152      // max bucket load ~37.5K entries; 80*49152*8B = 31.5MB (overlays xbuf)
#define CSR_REP 4         // blocks per bucket in k_csr (XCD-affine)

typedef __attribute__((ext_vector_type(8))) short short8;   // 8 bf16 in 4 VGPRs
typedef __attribute__((ext_vector_type(4))) float f32x4;    // MFMA accumulator

// fp32 -> bf16 round-to-nearest-even
static __device__ inline short f2bf(float f) {
    unsigned int u = __float_as_uint(f);
    unsigned int r = (u + 0x7FFFu + ((u >> 16) & 1u)) >> 16;
    return (short)r;
}
static __device__ inline float bf2f(unsigned short s) {
    return __uint_as_float(((unsigned int)s) << 16);
}
// deg^-1/2 with self-loop; same v_rsq_f32 the old k_dis used -> bit-identical numerics
static __device__ inline float disf(int c) {
    return rsqrtf(1.0f + (float)c);
}

// ---------------- setup: zero cnt + bucket counters + weight prep ----------------
// wts layout (shorts): WufT@0(8192) WpfT@8192(8192) c1T@16384(4096) c2T@20480(4096) W1T@24576(8192)
__global__ void k_setup(int* __restrict__ cnt,
                        const float* __restrict__ W_uf, const float* __restrict__ W_pf,
                        const float* __restrict__ c1, const float* __restrict__ c2,
                        const float* __restrict__ W1, short* __restrict__ wts) {
    int b = blockIdx.x;
    if (b < ZERO_BLK) {
        int i = b * 256 + threadIdx.x;
        if (i < 300032 + NBUK) cnt[i] = 0;   // cnt + gbin_cnt (contiguous)
        return;
    }
    int gid = (b - ZERO_BLK) * 256 + threadIdx.x;
    if (gid >= 32768) return;
    if (gid < 8192) {
        int n = gid >> 7, k = gid & 127;
        wts[gid] = f2bf(W_uf[k * 64 + n]);
    } else if (gid < 16384) {
        int i = gid - 8192; int n = i >> 7, k = i & 127;
        wts[gid] = f2bf(W_pf[k * 64 + n]);
    } else if (gid < 20480) {
        int i = gid - 16384; int n = i >> 6, k = i & 63;
        wts[gid] = f2bf(c1[k * 64 + n]);
    } else if (gid < 24576) {
        int i = gid - 20480; int n = i >> 6, k = i & 63;
        wts[gid] = f2bf(c2[k * 64 + n]);
    } else {
        int i = gid - 24576; int n = i >> 7, k = i & 127;
        wts[gid] = f2bf(W1[k * 64 + n]);
    }
}

// ---------------- CSR phase 1: LDS-binned edge scatter into per-bucket streams ----------------
// Append-only bucket streams -> lines fill completely -> coalesced ~16MB write (vs 121MB random).
__global__ __launch_bounds__(256) void k_bin(
    const int* __restrict__ ei, int* __restrict__ gcnt, int* __restrict__ gbin) {
    __shared__ int lcnt[NBUK];
    __shared__ int lbase[NBUK];
    int tid = threadIdx.x;
    if (tid < NBUK) lcnt[tid] = 0;
    __syncthreads();
    int e0 = (blockIdx.x * 256 + tid) * 4;
    bool act = e0 < N_EDGES;
    int d[8], s[8], rk[8], bk[8];
    if (act) {
        int4 uu = *(const int4*)(ei + e0);            // user ids
        int4 pp = *(const int4*)(ei + N_EDGES + e0);  // raw (un-offset) product ids — reference quirk
        d[0] = pp.x; s[0] = uu.x;  d[1] = uu.x; s[1] = pp.x;
        d[2] = pp.y; s[2] = uu.y;  d[3] = uu.y; s[3] = pp.y;
        d[4] = pp.z; s[4] = uu.z;  d[5] = uu.z; s[5] = pp.z;
        d[6] = pp.w; s[6] = uu.w;  d[7] = uu.w; s[7] = pp.w;
#pragma unroll
        for (int j = 0; j < 8; ++j) {
            bk[j] = d[j] / BNODES;                    // dest < 200000 always
            rk[j] = atomicAdd(&lcnt[bk[j]], 1);
        }
    }
    __syncthreads();
    if (tid < NBUK) lbase[tid] = atomicAdd(&gcnt[tid], lcnt[tid]);
    __syncthreads();
    if (act) {
#pragma unroll
        for (int j = 0; j < 8; ++j) {
            int pos = lbase[bk[j]] + rk[j];
            if (pos < BINCAP)                         // safety guard (expected max ~38K << 49152)
                *(int2*)(gbin + ((size_t)bk[j] * BINCAP + pos) * 2) = make_int2(d[j], s[j]);
        }
    }
}

// ---------------- CSR phase 2: per-bucket slot assignment, XCD-affine for L2 write merging ----------------
// Bucket's 400KB adj region stays resident in one XCD L2 -> slot writes merge before flush.
__global__ __launch_bounds__(256) void k_csr(
    const int* __restrict__ gcnt, const int* __restrict__ gbin,
    int* __restrict__ cnt, int* __restrict__ adj) {
    int i = blockIdx.x;
    int xcd = i & 7, k = i >> 3;              // blockIdx%8 ~ XCD (round-robin dispatch heuristic)
    int bucket = (k % (NBUK / 8)) * 8 + xcd;  // interleave heavy (dest<100K) buckets across XCDs
    int rep = k / (NBUK / 8);                 // [0, CSR_REP)
    int n = gcnt[bucket];
    const int* bb = gbin + (size_t)bucket * BINCAP * 2;
    const int stride = CSR_REP * 256;
    int idx = rep * 256 + threadIdx.x;
    for (; idx + 3 * stride < n; idx += 4 * stride) {   // 4 independent atomic round-trips in flight
        int2 e0 = *(const int2*)(bb + (size_t)(idx)*2);
        int2 e1 = *(const int2*)(bb + (size_t)(idx + stride) * 2);
        int2 e2 = *(const int2*)(bb + (size_t)(idx + 2 * stride) * 2);
        int2 e3 = *(const int2*)(bb + (size_t)(idx + 3 * stride) * 2);
        int s0 = atomicAdd(&cnt[e0.x], 1);
        int s1 = atomicAdd(&cnt[e1.x], 1);
        int s2 = atomicAdd(&cnt[e2.x], 1);
        int s3 = atomicAdd(&cnt[e3.x], 1);
        adj[(size_t)e0.x * CAP + s0] = e0.y;
        adj[(size_t)e1.x * CAP + s1] = e1.y;
        adj[(size_t)e2.x * CAP + s2] = e2.y;
        adj[(size_t)e3.x * CAP + s3] = e3.y;
    }
    for (; idx < n; idx += stride) {
        int2 e = *(const int2*)(bb + (size_t)idx * 2);
        int s = atomicAdd(&cnt[e.x], 1);
        adj[(size_t)e.x * CAP + s] = e.y;
    }
}

// ---------------- FUSED: x0 = feat@W + b + emb; h1' = dis*(x0@c1W) ----------------
// Single dispatch covers users AND products (wave-uniform branch on tile id).
// x0 never touches global memory: LDS retile (2.25 KB/wave) bridges the two MFMA GEMMs.
__global__ __launch_bounds__(256) void k_xform_c1(
    const float* __restrict__ user_feat, const float* __restrict__ prod_feat,
    const short* __restrict__ wts,
    const float* __restrict__ b_uf, const float* __restrict__ b_pf,
    const float* __restrict__ user_emb, const float* __restrict__ prod_emb,
    const int* __restrict__ cnt, unsigned short* __restrict__ h) {
    __shared__ unsigned short lds[4][16 * LDST];
    int tid = threadIdx.x;
    int wave = tid >> 6;
    int tile = blockIdx.x * 4 + wave;
    if (tile >= NT_ALL) tile = NT_ALL - 1;   // clamp: duplicate identical writes, keeps barrier safe
    int lane = tid & 63, ln = lane & 15, quad = lane >> 4;

    // per-wave operand selection (uniform within wave -> no divergence)
    const float* feat; const short* WT; const float* b; const float* emb;
    int node_off, mtile;
    if (tile < NT_U) {
        feat = user_feat; WT = wts;        b = b_uf; emb = user_emb; node_off = 0;         mtile = tile;
    } else {
        feat = prod_feat; WT = wts + 8192; b = b_pf; emb = prod_emb; node_off = NUM_USERS; mtile = tile - NT_U;
    }
    const short* c1T = wts + 16384;

    short8 Bx[4][4];
#pragma unroll
    for (int t = 0; t < 4; ++t)
#pragma unroll
        for (int kk = 0; kk < 4; ++kk)
            Bx[t][kk] = *(const short8*)(WT + ((t * 16 + ln) * 128 + kk * 32 + quad * 8));
    short8 Bc[4][2];
#pragma unroll
    for (int t = 0; t < 4; ++t)
#pragma unroll
        for (int kk = 0; kk < 2; ++kk)
            Bc[t][kk] = *(const short8*)(c1T + ((t * 16 + ln) * 64 + kk * 32 + quad * 8));
    float bv[4];
#pragma unroll
    for (int t = 0; t < 4; ++t) bv[t] = b[t * 16 + ln];

    int mbase = mtile * 16;
    const float* arow = feat + (size_t)(mbase + ln) * FDIM + quad * 8;

    f32x4 acc[4] = {{0.f,0.f,0.f,0.f},{0.f,0.f,0.f,0.f},{0.f,0.f,0.f,0.f},{0.f,0.f,0.f,0.f}};
#pragma unroll
    for (int kk = 0; kk < 4; ++kk) {
        float4 lo = *(const float4*)(arow + kk * 32);
        float4 hi = *(const float4*)(arow + kk * 32 + 4);
        short8 Af;
        Af[0] = f2bf(lo.x); Af[1] = f2bf(lo.y); Af[2] = f2bf(lo.z); Af[3] = f2bf(lo.w);
        Af[4] = f2bf(hi.x); Af[5] = f2bf(hi.y); Af[6] = f2bf(hi.z); Af[7] = f2bf(hi.w);
#pragma unroll
        for (int t = 0; t < 4; ++t)
            acc[t] = __builtin_amdgcn_mfma_f32_16x16x32_bf16(Af, Bx[t][kk], acc[t], 0, 0, 0);
    }
    // x0 epilogue -> LDS tile (bf16, same quantization the old memory round-trip applied)
#pragma unroll
    for (int r = 0; r < 4; ++r) {
        int node = mbase + quad * 4 + r;
#pragma unroll
        for (int t = 0; t < 4; ++t) {
            float v = acc[t][r] + bv[t] + emb[(size_t)node * EDIM + t * 16 + ln];
            lds[wave][(quad * 4 + r) * LDST + t * 16 + ln] = (unsigned short)f2bf(v);
        }
    }
    __syncthreads();
    // second GEMM: h1' = dis * (x0 @ c1W)
    f32x4 acch[4] = {{0.f,0.f,0.f,0.f},{0.f,0.f,0.f,0.f},{0.f,0.f,0.f,0.f},{0.f,0.f,0.f,0.f}};
#pragma unroll
    for (int kk = 0; kk < 2; ++kk) {
        short8 Af = *(const short8*)(&lds[wave][ln * LDST + kk * 32 + quad * 8]);
#pragma unroll
        for (int t = 0; t < 4; ++t)
            acch[t] = __builtin_amdgcn_mfma_f32_16x16x32_bf16(Af, Bc[t][kk], acch[t], 0, 0, 0);
    }
    float disv[4];
#pragma unroll
    for (int r = 0; r < 4; ++r) disv[r] = disf(cnt[node_off + mbase + quad * 4 + r]);
#pragma unroll
    for (int r = 0; r < 4; ++r) {
        int node = mbase + quad * 4 + r;
#pragma unroll
        for (int t = 0; t < 4; ++t)
            h[(size_t)(node_off + node) * EDIM + t * 16 + ln] =
                (unsigned short)f2bf(disv[r] * acch[t][r]);
    }
}

// ---------------- FUSED: x1 = relu(dis*(h1'[d]+Σ h1'[src]) + b1); h2' = dis*(x1@c2W) ----------------
__global__ __launch_bounds__(256) void k_gather_c2(
    const int* __restrict__ adj, const int* __restrict__ cnt,
    const unsigned short* __restrict__ h,
    const float* __restrict__ b1, const short* __restrict__ c2T,
    unsigned short* __restrict__ hout) {
    __shared__ unsigned short lds[4][16 * LDST];
    int tid = threadIdx.x;
    int wave = tid >> 6;
    int tile = blockIdx.x * 4 + wave;
    if (tile >= N_NODES / 16) tile = N_NODES / 16 - 1;  // clamp (benign dup writes)
    int lane = tid & 63, ln = lane & 15, quad = lane >> 4;
    const unsigned int* hp = (const unsigned int*)h;    // bf16x2 view, row stride 32

    short8 Bc[4][2];
#pragma unroll
    for (int t = 0; t < 4; ++t)
#pragma unroll
        for (int kk = 0; kk < 2; ++kk)
            Bc[t][kk] = *(const short8*)(c2T + ((t * 16 + ln) * 64 + kk * 32 + quad * 8));

    int mbase = tile * 16;
    float2 bb0 = ((const float2*)b1)[ln];        // feats 2ln, 2ln+1
    float2 bb1 = ((const float2*)b1)[16 + ln];   // feats 32+2ln, 32+2ln+1

#pragma unroll 1
    for (int it = 0; it < 4; ++it) {
        int d = mbase + it * 4 + quad;
        const unsigned int* hrow = hp + (size_t)d * 32;
        unsigned int s0 = hrow[ln], s1 = hrow[16 + ln];          // self-loop term
        float a0 = bf2f((unsigned short)s0);
        float a1 = bf2f((unsigned short)(s0 >> 16));
        float a2 = bf2f((unsigned short)s1);
        float a3 = bf2f((unsigned short)(s1 >> 16));
        int cd = cnt[d];
        const int* ap = adj + (size_t)d * CAP;
        int i = 0;
        for (; i + 1 < cd; i += 2) {                             // 4 gathers in flight/lane
            int r0 = ap[i], r1 = ap[i + 1];
            unsigned int p00 = hp[(size_t)r0 * 32 + ln];
            unsigned int p01 = hp[(size_t)r0 * 32 + 16 + ln];
            unsigned int p10 = hp[(size_t)r1 * 32 + ln];
            unsigned int p11 = hp[(size_t)r1 * 32 + 16 + ln];
            a0 += bf2f((unsigned short)p00) + bf2f((unsigned short)p10);
            a1 += bf2f((unsigned short)(p00 >> 16)) + bf2f((unsigned short)(p10 >> 16));
            a2 += bf2f((unsigned short)p01) + bf2f((unsigned short)p11);
            a3 += bf2f((unsigned short)(p01 >> 16)) + bf2f((unsigned short)(p11 >> 16));
        }
        if (i < cd) {
            int r0 = ap[i];
            unsigned int p00 = hp[(size_t)r0 * 32 + ln];
            unsigned int p01 = hp[(size_t)r0 * 32 + 16 + ln];
            a0 += bf2f((unsigned short)p00);
            a1 += bf2f((unsigned short)(p00 >> 16));
            a2 += bf2f((unsigned short)p01);
            a3 += bf2f((unsigned short)(p01 >> 16));
        }
        float dv = disf(cd);
        float v0 = fmaxf(fmaf(dv, a0, bb0.x), 0.f);
        float v1 = fmaxf(fmaf(dv, a1, bb0.y), 0.f);
        float v2 = fmaxf(fmaf(dv, a2, bb1.x), 0.f);
        float v3 = fmaxf(fmaf(dv, a3, bb1.y), 0.f);
        unsigned int* lrow = (unsigned int*)&lds[wave][(it * 4 + quad) * LDST];
        lrow[ln] = ((unsigned int)(unsigned short)f2bf(v1) << 16)
                 | (unsigned int)(unsigned short)f2bf(v0);
        lrow[16 + ln] = ((unsigned int)(unsigned short)f2bf(v3) << 16)
                      | (unsigned int)(unsigned short)f2bf(v2);
    }
    __syncthreads();
    // h2' = dis * (x1 @ c2W)
    f32x4 acc[4] = {{0.f,0.f,0.f,0.f},{0.f,0.f,0.f,0.f},{0.f,0.f,0.f,0.f},{0.f,0.f,0.f,0.f}};
#pragma unroll
    for (int kk = 0; kk < 2; ++kk) {
        short8 Af = *(const short8*)(&lds[wave][ln * LDST + kk * 32 + quad * 8]);
#pragma unroll
        for (int t = 0; t < 4; ++t)
            acc[t] = __builtin_amdgcn_mfma_f32_16x16x32_bf16(Af, Bc[t][kk], acc[t], 0, 0, 0);
    }
    float disv[4];
#pragma unroll
    for (int r = 0; r < 4; ++r) disv[r] = disf(cnt[mbase + quad * 4 + r]);
#pragma unroll
    for (int r = 0; r < 4; ++r) {
        int node = mbase + quad * 4 + r;
#pragma unroll
        for (int t = 0; t < 4; ++t)
            hout[(size_t)node * EDIM + t * 16 + ln] = (unsigned short)f2bf(disv[r] * acc[t][r]);
    }
}

// ---------------- gather + finish (conv2 output): x[d] = dis[d]*(h'[d]+Σ h'[src]) + b ----------------
__global__ __launch_bounds__(256) void k_gather(
    const int* __restrict__ adj, const int* __restrict__ cnt,
    const unsigned short* __restrict__ h,
    const float* __restrict__ b, unsigned short* __restrict__ xout, int relu) {
    int d = blockIdx.x * 4 + (threadIdx.x >> 6);
    if (d >= N_NODES) return;
    int l = threadIdx.x & 63;
    int half = l >> 5, c2 = l & 31;              // feature pair c2 -> feats {2c2, 2c2+1}
    const unsigned int* hp = (const unsigned int*)h;   // bf16x2 view, row stride 32

    float ax = 0.f, ay = 0.f;
    if (half == 0) {                              // self-loop term, counted once
        unsigned int pr = hp[(size_t)d * 32 + c2];
        ax = bf2f((unsigned short)pr);
        ay = bf2f((unsigned short)(pr >> 16));
    }
    int c = cnt[d];
    const int* ap = adj + (size_t)d * CAP;
    int i = 0;
    for (; i + 3 < c; i += 4) {
        int s0 = ap[i + half];
        int s1 = ap[i + 2 + half];
        unsigned int p0 = hp[(size_t)s0 * 32 + c2];
        unsigned int p1 = hp[(size_t)s1 * 32 + c2];
        ax += bf2f((unsigned short)p0) + bf2f((unsigned short)p1);
        ay += bf2f((unsigned short)(p0 >> 16)) + bf2f((unsigned short)(p1 >> 16));
    }
    if (i + half < c) {
        unsigned int p0 = hp[(size_t)ap[i + half] * 32 + c2];
        ax += bf2f((unsigned short)p0);
        ay += bf2f((unsigned short)(p0 >> 16));
    }
    if (i + 2 + half < c) {
        unsigned int p0 = hp[(size_t)ap[i + 2 + half] * 32 + c2];
        ax += bf2f((unsigned short)p0);
        ay += bf2f((unsigned short)(p0 >> 16));
    }
    ax += __shfl_xor(ax, 32, 64);                 // combine the two halves
    ay += __shfl_xor(ay, 32, 64);
    float dv = disf(c);
    float2 bb = ((const float2*)b)[c2];
    float v0 = fmaf(dv, ax, bb.x);
    float v1 = fmaf(dv, ay, bb.y);
    if (relu) { v0 = fmaxf(v0, 0.f); v1 = fmaxf(v1, 0.f); }
    if (half == 0) {
        unsigned int pk = ((unsigned int)(unsigned short)f2bf(v1) << 16)
                        | (unsigned int)(unsigned short)f2bf(v0);
        ((unsigned int*)xout)[(size_t)d * 32 + c2] = pk;
    }
}

// ---------------- edge predictor via bf16 MFMA, ei prefetch + hoisted A loads ----------------
__global__ __launch_bounds__(256) void k_pred_mfma(
    const int* __restrict__ ei, const unsigned short* __restrict__ x,
    const short* __restrict__ W1T, const float* __restrict__ b1,
    const float* __restrict__ W2, const float* __restrict__ b2,
    float* __restrict__ preds) {
    int tid = threadIdx.x;
    int wave = tid >> 6, lane = tid & 63;
    int ln = lane & 15, quad = lane >> 4;

    short8 Bf[4][4];
#pragma unroll
    for (int t = 0; t < 4; ++t)
#pragma unroll
        for (int kk = 0; kk < 4; ++kk)
            Bf[t][kk] = *(const short8*)(W1T + ((t * 16 + ln) * 128 + kk * 32 + quad * 8));

    float b1v[4], W2v[4];
#pragma unroll
    for (int t = 0; t < 4; ++t) {
        b1v[t] = b1[t * 16 + ln];
        W2v[t] = W2[t * 16 + ln];
    }
    float b2s = b2[0];

    const int n_tiles = N_EDGES / 16;
    int gw = blockIdx.x * 4 + wave;
    int nwaves = gridDim.x * 4;

    int cu = 0, cp = 0;
    if (gw < n_tiles) {
        cu = ei[gw * 16 + ln];
        cp = ei[N_EDGES + gw * 16 + ln] + NUM_USERS;
    }
    for (int tile = gw; tile < n_tiles; tile += nwaves) {
        int u = cu, p = cp;
        int nt = tile + nwaves;
        if (nt < n_tiles) {                       // prefetch next tile's indices
            cu = ei[nt * 16 + ln];
            cp = ei[N_EDGES + nt * 16 + ln] + NUM_USERS;
        }
        short8 Af[4];                             // all 4 A loads in flight
        Af[0] = *(const short8*)(x + (size_t)u * EDIM + quad * 8);
        Af[1] = *(const short8*)(x + (size_t)u * EDIM + 32 + quad * 8);
        Af[2] = *(const short8*)(x + (size_t)p * EDIM + quad * 8);
        Af[3] = *(const short8*)(x + (size_t)p * EDIM + 32 + quad * 8);

        f32x4 acc[4] = {{0.f,0.f,0.f,0.f},{0.f,0.f,0.f,0.f},{0.f,0.f,0.f,0.f},{0.f,0.f,0.f,0.f}};
#pragma unroll
        for (int kk = 0; kk < 4; ++kk)
#pragma unroll
            for (int t = 0; t < 4; ++t)
                acc[t] = __builtin_amdgcn_mfma_f32_16x16x32_bf16(Af[kk], Bf[t][kk], acc[t], 0, 0, 0);

        float out[4];
#pragma unroll
        for (int r = 0; r < 4; ++r) {
            float part = 0.f;
#pragma unroll
            for (int t = 0; t < 4; ++t) {
                float hv = fmaxf(acc[t][r] + b1v[t], 0.f);
                part = fmaf(hv, W2v[t], part);
            }
            part += __shfl_xor(part, 1, 64);
            part += __shfl_xor(part, 2, 64);
            part += __shfl_xor(part, 4, 64);
            part += __shfl_xor(part, 8, 64);
            out[r] = part;
        }
        if (ln == 0) {
            int ebase = tile * 16;
#pragma unroll
            for (int r = 0; r < 4; ++r) {
                float logit = out[r] + b2s;
                preds[ebase + quad * 4 + r] = 5.f / (1.f + expf(-logit));
            }
        }
    }
}

extern "C" void kernel_launch(void* const* d_in, const int* in_sizes, int n_in,
                              void* d_out, int out_size, void* d_ws, size_t ws_size,
                              hipStream_t stream) {
    const int*   ei        = (const int*)d_in[0];
    const float* user_feat = (const float*)d_in[1];
    const float* prod_feat = (const float*)d_in[2];
    const float* user_emb  = (const float*)d_in[3];
    const float* prod_emb  = (const float*)d_in[4];
    const float* W_uf      = (const float*)d_in[5];
    const float* b_uf      = (const float*)d_in[6];
    const float* W_pf      = (const float*)d_in[7];
    const float* b_pf      = (const float*)d_in[8];
    const float* conv1_W   = (const float*)d_in[9];
    const float* conv1_b   = (const float*)d_in[10];
    const float* conv2_W   = (const float*)d_in[11];
    const float* conv2_b   = (const float*)d_in[12];
    const float* pred_W1   = (const float*)d_in[13];
    const float* pred_b1   = (const float*)d_in[14];
    const float* pred_W2   = (const float*)d_in[15];
    const float* pred_b2   = (const float*)d_in[16];

    // workspace layout (4-byte units)
    int* ws_i = (int*)d_ws;
    int*   cnt  = ws_i;                            // 300032 + NBUK bucket counters right after
    int*   gcnt = ws_i + 300032;                   // 80 ints (zeroed with cnt)
    int*   adj  = ws_i + 600064;                   // 300032*40 = 12,001,280
    unsigned short* xbuf = (unsigned short*)(ws_i + 12601344);  // 38.4MB; gbin overlays (dead until gather_c2)
    int*   gbin = ws_i + 12601344;                 // 80*49152 int2 entries = 31.5MB
    unsigned short* hbuf = (unsigned short*)(ws_i + 22201344);  // 38.4MB
    short* wts = (short*)(ws_i + 31801344);        // 32768 bf16
    float* preds = (float*)d_out;

    // setup (zero cnt+gcnt + weight prep), then two-phase binned CSR build
    k_setup<<<ZERO_BLK + 128, 256, 0, stream>>>(cnt, W_uf, W_pf, conv1_W, conv2_W, pred_W1, wts);
    k_bin<<<(N_EDGES / 4 + 255) / 256, 256, 0, stream>>>(ei, gcnt, gbin);
    k_csr<<<NBUK * CSR_REP, 256, 0, stream>>>(gcnt, gbin, cnt, adj);

    // fused node-transform + conv1 GEMM (users+products, one dispatch) -> hbuf = h1'
    k_xform_c1<<<(NT_ALL + 3) / 4, 256, 0, stream>>>(user_feat, prod_feat, wts,
                                                     b_uf, b_pf, user_emb, prod_emb,
                                                     cnt, hbuf);

    // fused conv1-gather + conv2 GEMM -> xbuf = h2' (gbin dead from here); x1 never hits memory
    k_gather_c2<<<(18750 + 3) / 4, 256, 0, stream>>>(adj, cnt, hbuf, conv1_b,
                                                     wts + 20480, xbuf);
    // conv2 gather -> hbuf = x2 (final node embeddings)
    k_gather<<<N_NODES / 4, 256, 0, stream>>>(adj, cnt, xbuf, conv2_b, hbuf, 0);

    // predictor
    k_pred_mfma<<<2048, 256, 0, stream>>>(ei, hbuf, wts + 24576, pred_b1, pred_W2, pred_b2, preds);
}